// Round 6
// baseline (361.747 us; speedup 1.0000x reference)
//
#include <hip/hip_runtime.h>

// SpiralConv conv block: per-channel complex first-order recurrence
//   h[n] = c*h[n-1] + x[n],  h[-1] = last_conv_init[d],  out = Re(h)*x
// with c_d = exp(-exp(lmlg_d)) * e^{i*theta_d}.
//
// R6: single-dispatch chained scan with decoupled lookback (rocPRIM
// pattern). Grid 512 = NC(128) x B(4); __launch_bounds__(256,2) caps
// VGPR at 256 -> >=2 blocks/CU -> all 512 blocks co-resident, so the
// flag spin can never deadlock (no dispatch-order assumption).
// x is read once (kept in registers across the lookback). Cross-XCD
// visibility via agent-scope release/acquire atomics on flags.

#define L_  4096
#define B_  4
#define D_  1024
#define BD_ (B_ * D_)     // 4096
#define NC  128           // chunks
#define CH  32            // steps per chunk

// flag values: 0 = nothing, 1 = aggregate ready, 2 = inclusive ready

__global__ __launch_bounds__(256, 2) void sc_lookback(
    const float* __restrict__ x,
    const float* __restrict__ lmlg,
    const float* __restrict__ theta,
    const float* __restrict__ init,
    float* __restrict__ out,
    float2* __restrict__ agg,            // [NC][B][D]
    float2* __restrict__ inc,            // [NC][B][D]
    unsigned int* __restrict__ flags) {  // [NC][B]
  const int t    = threadIdx.x;
  const int k    = blockIdx.x / B_;
  const int b    = blockIdx.x % B_;
  const int d0   = t * 4;
  const int lane = t & 63;

  float4 lg = *(const float4*)(lmlg + d0);
  float4 th = *(const float4*)(theta + d0);
  // c = gamma * e^{i theta},   Cc = c^CH (closed form)
  float cr[4], ci[4], Cr[4], Ci[4];
  {
    float e[4] = {expf(lg.x), expf(lg.y), expf(lg.z), expf(lg.w)};
    float ta[4] = {th.x, th.y, th.z, th.w};
#pragma unroll
    for (int c = 0; c < 4; ++c) {
      float g = expf(-e[c]);
      cr[c] = g * cosf(ta[c]);  ci[c] = g * sinf(ta[c]);
      float gC = expf(-e[c] * (float)CH);
      Cr[c] = gC * cosf(ta[c] * (float)CH);
      Ci[c] = gC * sinf(ta[c] * (float)CH);
    }
  }

  // ---- load chunk into registers (x read exactly once) ----
  const size_t base = (size_t)k * CH * BD_ + (size_t)b * D_ + d0;
  float4 xv[CH];
#pragma unroll
  for (int j = 0; j < CH; ++j)
    xv[j] = *(const float4*)(x + base + (size_t)j * BD_);

  // ---- chunk aggregate S = fold(0; s = c*s + x) ----
  float sr[4] = {0.f,0.f,0.f,0.f}, si[4] = {0.f,0.f,0.f,0.f};
#pragma unroll
  for (int j = 0; j < CH; ++j) {
    const float* xa = &xv[j].x;
#pragma unroll
    for (int c = 0; c < 4; ++c) {
      float nr = fmaf(cr[c], sr[c], fmaf(-ci[c], si[c], xa[c]));
      float ni = fmaf(cr[c], si[c], ci[c] * sr[c]);
      sr[c] = nr; si[c] = ni;
    }
  }

  // ---- publish aggregate (flag=1) ----
  {
    float2* ap = agg + ((size_t)k * B_ + b) * D_ + d0;
#pragma unroll
    for (int c = 0; c < 4; ++c) ap[c] = make_float2(sr[c], si[c]);
  }
  __threadfence();
  __syncthreads();
  if (t == 0)
    __hip_atomic_store(&flags[k * B_ + b], 1u, __ATOMIC_RELEASE,
                       __HIP_MEMORY_SCOPE_AGENT);

  // ---- lookback: P = H_{k-1} (state entering this chunk) ----
  float4 iv = *(const float4*)(init + d0);
  float Pr[4] = {iv.x, iv.y, iv.z, iv.w};
  float Pi[4] = {0.f, 0.f, 0.f, 0.f};

  // phase a: find highest j* < k with an inclusive published (no spin)
  int jstar = -1;
  for (int bj = k - 1; bj >= 0; bj -= 64) {
    int j = bj - lane;                       // lane 0 = highest index
    unsigned f = 0u;
    if (j >= 0)
      f = __hip_atomic_load(&flags[j * B_ + b], __ATOMIC_ACQUIRE,
                            __HIP_MEMORY_SCOPE_AGENT);
    unsigned long long m2 = __ballot(j >= 0 && f == 2u);
    if (m2) { jstar = bj - (__ffsll((unsigned long long)m2) - 1); break; }
  }
  if (jstar >= 0) {
    const float2* ip = inc + ((size_t)jstar * B_ + b) * D_ + d0;
#pragma unroll
    for (int c = 0; c < 4; ++c) { float2 h = ip[c]; Pr[c] = h.x; Pi[c] = h.y; }
  }

  // phase b: fold forward from j*+1; spin per 64-window until all >=1;
  // shortcut onto any inclusive that appeared meanwhile.
  for (int w0 = jstar + 1; w0 < k; w0 += 64) {
    const int wend = (w0 + 64 < k) ? (w0 + 64) : k;
    const int idx  = w0 + lane;
    const bool val = idx < k;
    unsigned f;
    unsigned long long m0;
    do {
      f = val ? __hip_atomic_load(&flags[idx * B_ + b], __ATOMIC_ACQUIRE,
                                  __HIP_MEMORY_SCOPE_AGENT)
              : 1u;
      m0 = __ballot(f == 0u);
    } while (m0 != 0ull);
    unsigned long long m2 = __ballot(val && f == 2u);
    int q0 = w0;
    if (m2) {
      int j2 = w0 + (63 - __clzll(m2));      // highest inclusive in window
      const float2* ip = inc + ((size_t)j2 * B_ + b) * D_ + d0;
#pragma unroll
      for (int c = 0; c < 4; ++c) { float2 h = ip[c]; Pr[c] = h.x; Pi[c] = h.y; }
      q0 = j2 + 1;
    }
    for (int q = q0; q < wend; ++q) {
      const float2* sp = agg + ((size_t)q * B_ + b) * D_ + d0;
      float2 s0 = sp[0], s1 = sp[1], s2 = sp[2], s3 = sp[3];
      float sx[4] = {s0.x, s1.x, s2.x, s3.x};
      float sy[4] = {s0.y, s1.y, s2.y, s3.y};
#pragma unroll
      for (int c = 0; c < 4; ++c) {
        float nr = fmaf(Cr[c], Pr[c], fmaf(-Ci[c], Pi[c], sx[c]));
        float ni = fmaf(Cr[c], Pi[c], fmaf(Ci[c], Pr[c], sy[c]));
        Pr[c] = nr; Pi[c] = ni;
      }
    }
  }

  // ---- publish inclusive H_k = Cc*P + S (flag=2) ----
  {
    float2* ip = inc + ((size_t)k * B_ + b) * D_ + d0;
#pragma unroll
    for (int c = 0; c < 4; ++c) {
      float nr = fmaf(Cr[c], Pr[c], fmaf(-Ci[c], Pi[c], sr[c]));
      float ni = fmaf(Cr[c], Pi[c], fmaf(Ci[c], Pr[c], si[c]));
      ip[c] = make_float2(nr, ni);
    }
  }
  __threadfence();
  __syncthreads();
  if (t == 0)
    __hip_atomic_store(&flags[k * B_ + b], 2u, __ATOMIC_RELEASE,
                       __HIP_MEMORY_SCOPE_AGENT);

  // ---- replay chunk from P, emit out = Re(h)*x ----
#pragma unroll
  for (int j = 0; j < CH; ++j) {
    const float* xa = &xv[j].x;
    float4 res; float* ra = &res.x;
#pragma unroll
    for (int c = 0; c < 4; ++c) {
      float nr = fmaf(cr[c], Pr[c], fmaf(-ci[c], Pi[c], xa[c]));
      float ni = fmaf(cr[c], Pi[c], ci[c] * Pr[c]);
      Pr[c] = nr; Pi[c] = ni;
      ra[c] = nr * xa[c];
    }
    *(float4*)(out + base + (size_t)j * BD_) = res;
  }
}

// ------------------------------------------------------------- fallback ----
// ws-free fully sequential per-column scan (used only if ws_size is tiny).
__global__ __launch_bounds__(256) void sc_full(
    const float* __restrict__ x, const float* __restrict__ lmlg,
    const float* __restrict__ theta, const float* __restrict__ init,
    float* __restrict__ out) {
  const int idx = blockIdx.x * 256 + threadIdx.x;
  const int d   = idx & (D_ - 1);
  float g = expf(-expf(lmlg[d]));
  float cr = g * cosf(theta[d]), ci = g * sinf(theta[d]);
  float hr = init[d], hi = 0.f;
  const float* xp = x + idx;
  float*       op = out + idx;
  for (int n = 0; n < L_; ++n) {
    float xv = xp[(size_t)n * BD_];
    float nr = fmaf(cr, hr, fmaf(-ci, hi, xv));
    float ni = fmaf(cr, hi, ci * hr);
    hr = nr; hi = ni;
    op[(size_t)n * BD_] = nr * xv;
  }
}

// ---------------------------------------------------------------------------
extern "C" void kernel_launch(void* const* d_in, const int* in_sizes, int n_in,
                              void* d_out, int out_size, void* d_ws, size_t ws_size,
                              hipStream_t stream) {
  const float* x     = (const float*)d_in[0];
  const float* lmlg  = (const float*)d_in[1];
  const float* theta = (const float*)d_in[2];
  const float* init  = (const float*)d_in[3];
  float* out = (float*)d_out;

  const size_t flag_bytes = 8192;                       // NC*B*4 = 2 KiB, padded
  const size_t pay        = (size_t)NC * BD_ * sizeof(float2);   // 4 MiB
  const size_t need       = flag_bytes + 2 * pay;

  if (ws_size >= need) {
    unsigned int* flags = (unsigned int*)d_ws;
    float2* agg = (float2*)((char*)d_ws + flag_bytes);
    float2* inc = agg + (size_t)NC * BD_;
    hipMemsetAsync(flags, 0, NC * B_ * sizeof(unsigned int), stream);
    sc_lookback<<<NC * B_, 256, 0, stream>>>(x, lmlg, theta, init, out,
                                             agg, inc, flags);
  } else {
    sc_full<<<BD_ / 256, 256, 0, stream>>>(x, lmlg, theta, init, out);
  }
}